// Round 5
// baseline (49.981 us; speedup 1.0000x reference)
//
#include <hip/hip_runtime.h>
#include <math.h>

#define C_CLS   19
#define H_IN    97
#define W_IN    97
#define HW_IN   (H_IN * W_IN)
#define CHW_IN  (C_CLS * HW_IN)
#define H_OUT   769
#define W_OUT   769
#define N_BATCH 4
#define NPIX    (N_BATCH * H_OUT * W_OUT)
#define IGNORE_LBL 255
#define MIN_KEPT   100000
#define NHI     110          // histogram bins for p in (0.7, 1.0]
#define ACC_STRIDE 1024      // floats per pred histogram block in ws
#define NSETS   64           // striped accumulator sets (1 cache line each)
#define SET_BASE 2048        // ws float offset of striped sets
#define THR2    0.51457317f  // -log2(0.7); p <= 0.7  <=>  d = log2(s)-lt2 >= THR2
#define LN2     0.69314718f
#define LOG2E   1.44269504f
#define ROWP    100          // padded LDS row length (>= 98)

// Cityscapes class weights
__device__ const float c_class_w[C_CLS] = {
    0.8373f, 0.918f,  0.866f,  1.0345f, 1.0166f, 0.9969f, 0.9754f,
    1.0489f, 0.8786f, 1.0023f, 0.9539f, 0.9843f, 1.1116f, 0.9037f,
    1.0865f, 1.0955f, 1.0865f, 1.1529f, 1.0507f};

// ws layout (floats):
// [4..333]            hist pred1: cnt / sum_w / sum_wnll  (stride 110 each)
// [1028..1357]        hist pred2
// [2048 + s*16 + k]   striped accumulator set s (k: 0=nv 1=w1 2=wlp1 3=cle1
//                                                   4=w2 5=wlp2 6=cle2)

__global__ __launch_bounds__(256) void ohem_row(
    const float* __restrict__ pred1, const float* __restrict__ pred2,
    const int* __restrict__ target, float* __restrict__ ws)
{
    const int row = blockIdx.x;           // 0 .. 4*769-1
    const int n   = row / H_OUT;
    const int y   = row - n * H_OUT;
    const int tid = threadIdx.x;

    __shared__ float ry[2][C_CLS][ROWP];  // y-interp'd rows, pre-scaled by log2e
    __shared__ float wtab[2][C_CLS];      // [0]=w, [1]=w*ln2
    __shared__ float sh_red[4][8];

    if (tid < C_CLS) {
        float w = c_class_w[tid];
        wtab[0][tid] = w;
        wtab[1][tid] = w * LN2;
    }

    const float scl = (float)H_IN / (float)H_OUT;

    // ---- uniform y-interp params for this output row ----
    float sy = fmaxf(fmaf((float)y + 0.5f, scl, -0.5f), 0.0f);
    int   y0 = min((int)sy, H_IN - 1);
    float fy = sy - (float)y0;
    int   y1 = min(y0 + 1, H_IN - 1);

    // ---- stage y-interpolated (and log2e-scaled) rows into LDS ----
    const float* __restrict__ b1 = pred1 + (size_t)n * CHW_IN;
    const float* __restrict__ b2 = pred2 + (size_t)n * CHW_IN;
    for (int j = tid; j < C_CLS * W_IN; j += 256) {
        int c = j / W_IN;
        int x = j - c * W_IN;
        int o0 = c * HW_IN + y0 * W_IN + x;
        int o1 = c * HW_IN + y1 * W_IN + x;
        float a0 = b1[o0], a1 = b1[o1];
        float c0 = b2[o0], c1 = b2[o1];
        float r1 = fmaf(fy, a1 - a0, a0) * LOG2E;
        float r2 = fmaf(fy, c1 - c0, c0) * LOG2E;
        ry[0][c][x] = r1;
        ry[1][c][x] = r2;
        if (x == W_IN - 1) {              // pad so x0+1 read is safe & exact
            ry[0][c][W_IN] = r1;
            ry[1][c][W_IN] = r2;
        }
    }
    __syncthreads();

    // ---- per-pixel pass over this output row ----
    float a_nv = 0.0f;
    float a_w1 = 0.0f, a_wlp1 = 0.0f, a_cle1 = 0.0f;
    float a_w2 = 0.0f, a_wlp2 = 0.0f, a_cle2 = 0.0f;
    const int rowbase = (n * H_OUT + y) * W_OUT;

    #pragma unroll
    for (int i = 0; i < 4; ++i) {
        int x = tid + i * 256;
        if (x < W_OUT) {
            int t = target[rowbase + x];
            bool valid = (t != IGNORE_LBL);
            int ts = valid ? t : 0;

            float sx = fmaxf(fmaf((float)x + 0.5f, scl, -0.5f), 0.0f);
            int   x0 = min((int)sx, W_IN - 1);
            float fx = sx - (float)x0;

            // sum of 2^v over channels, 4 independent partials per pred
            float p1a = 0.f, p1b = 0.f, p1c = 0.f, p1d = 0.f;
            float p2a = 0.f, p2b = 0.f, p2c = 0.f, p2d = 0.f;
            #pragma unroll
            for (int c = 0; c < 16; c += 4) {
                {
                    float a0 = ry[0][c+0][x0], a1 = ry[0][c+0][x0+1];
                    p1a += exp2f(fmaf(fx, a1 - a0, a0));
                    float q0 = ry[1][c+0][x0], q1 = ry[1][c+0][x0+1];
                    p2a += exp2f(fmaf(fx, q1 - q0, q0));
                }
                {
                    float a0 = ry[0][c+1][x0], a1 = ry[0][c+1][x0+1];
                    p1b += exp2f(fmaf(fx, a1 - a0, a0));
                    float q0 = ry[1][c+1][x0], q1 = ry[1][c+1][x0+1];
                    p2b += exp2f(fmaf(fx, q1 - q0, q0));
                }
                {
                    float a0 = ry[0][c+2][x0], a1 = ry[0][c+2][x0+1];
                    p1c += exp2f(fmaf(fx, a1 - a0, a0));
                    float q0 = ry[1][c+2][x0], q1 = ry[1][c+2][x0+1];
                    p2c += exp2f(fmaf(fx, q1 - q0, q0));
                }
                {
                    float a0 = ry[0][c+3][x0], a1 = ry[0][c+3][x0+1];
                    p1d += exp2f(fmaf(fx, a1 - a0, a0));
                    float q0 = ry[1][c+3][x0], q1 = ry[1][c+3][x0+1];
                    p2d += exp2f(fmaf(fx, q1 - q0, q0));
                }
            }
            #pragma unroll
            for (int c = 16; c < C_CLS; ++c) {
                float a0 = ry[0][c][x0], a1 = ry[0][c][x0+1];
                p1a += exp2f(fmaf(fx, a1 - a0, a0));
                float q0 = ry[1][c][x0], q1 = ry[1][c][x0+1];
                p2a += exp2f(fmaf(fx, q1 - q0, q0));
            }
            float s1 = (p1a + p1b) + (p1c + p1d);
            float s2 = (p2a + p2b) + (p2c + p2d);

            // true-class (log2-scaled) logit via dynamic LDS read
            float l0 = ry[0][ts][x0], l1 = ry[0][ts][x0+1];
            float lt1 = fmaf(fx, l1 - l0, l0);
            float g0 = ry[1][ts][x0], g1 = ry[1][ts][x0+1];
            float lt2 = fmaf(fx, g1 - g0, g0);

            if (valid) {
                a_nv += 1.0f;
                float w   = wtab[0][ts];
                float wl2 = wtab[1][ts];
                float d1 = __log2f(s1) - lt1;   // nll = ln2 * d
                float d2 = __log2f(s2) - lt2;

                if (d1 >= THR2) {               // p1 <= 0.7
                    a_w1 += w; a_wlp1 = fmaf(wl2, d1, a_wlp1); a_cle1 += 1.0f;
                } else {                        // rare: direct global hist
                    float p = exp2f(-d1);
                    int b = min(max((int)((p - 0.7f) * (109.0f / 0.3f)), 0), NHI - 1);
                    atomicAdd(&ws[4 + b],   1.0f);
                    atomicAdd(&ws[114 + b], w);
                    atomicAdd(&ws[224 + b], wl2 * d1);
                }
                if (d2 >= THR2) {               // p2 <= 0.7
                    a_w2 += w; a_wlp2 = fmaf(wl2, d2, a_wlp2); a_cle2 += 1.0f;
                } else {
                    float p = exp2f(-d2);
                    int b = min(max((int)((p - 0.7f) * (109.0f / 0.3f)), 0), NHI - 1);
                    atomicAdd(&ws[ACC_STRIDE + 4 + b],   1.0f);
                    atomicAdd(&ws[ACC_STRIDE + 114 + b], w);
                    atomicAdd(&ws[ACC_STRIDE + 224 + b], wl2 * d2);
                }
            }
        }
    }

    // ---- wave butterfly reduce, 7 values ----
    #pragma unroll
    for (int off = 32; off > 0; off >>= 1) {
        a_nv   += __shfl_down(a_nv, off);
        a_w1   += __shfl_down(a_w1, off);
        a_wlp1 += __shfl_down(a_wlp1, off);
        a_cle1 += __shfl_down(a_cle1, off);
        a_w2   += __shfl_down(a_w2, off);
        a_wlp2 += __shfl_down(a_wlp2, off);
        a_cle2 += __shfl_down(a_cle2, off);
    }
    int lane = tid & 63;
    int wv   = tid >> 6;
    if (lane == 0) {
        sh_red[wv][0] = a_nv;
        sh_red[wv][1] = a_w1; sh_red[wv][2] = a_wlp1; sh_red[wv][3] = a_cle1;
        sh_red[wv][4] = a_w2; sh_red[wv][5] = a_wlp2; sh_red[wv][6] = a_cle2;
    }
    __syncthreads();
    if (tid == 0) {
        float r[7] = {0, 0, 0, 0, 0, 0, 0};
        #pragma unroll
        for (int i = 0; i < 4; ++i)
            #pragma unroll
            for (int j = 0; j < 7; ++j) r[j] += sh_red[i][j];
        // striped accumulator: one 64B line per set
        float* acc = ws + SET_BASE + (blockIdx.x & (NSETS - 1)) * 16;
        #pragma unroll
        for (int j = 0; j < 7; ++j) atomicAdd(&acc[j], r[j]);
    }
}

__global__ void ohem_finalize(const float* __restrict__ ws, float* __restrict__ out)
{
    // single 64-thread block: reduce 64 striped sets, then OHEM logic on lane 0
    int lane = threadIdx.x;   // 0..63
    float v[8];
    #pragma unroll
    for (int k = 0; k < 8; ++k) v[k] = ws[SET_BASE + lane * 16 + k];
    #pragma unroll
    for (int off = 32; off > 0; off >>= 1) {
        #pragma unroll
        for (int k = 0; k < 8; ++k) v[k] += __shfl_down(v[k], off);
    }
    if (lane != 0) return;

    float nv = v[0];
    float loss[2];
    for (int pr = 0; pr < 2; ++pr) {
        const float* a = ws + pr * ACC_STRIDE;
        float sw   = pr ? v[4] : v[1];
        float swlp = pr ? v[5] : v[2];
        float cle  = pr ? v[6] : v[3];
        float l;
        if (nv <= (float)MIN_KEPT) {
            float tw = sw, twlp = swlp;
            for (int b = 0; b < NHI; ++b) { tw += a[114 + b]; twlp += a[224 + b]; }
            l = twlp / tw;
        } else if (cle >= (float)MIN_KEPT) {
            l = swlp / sw;
        } else {
            float cum = cle, tw = sw, twlp = swlp;
            for (int b = 0; b < NHI; ++b) {
                cum  += a[4 + b];
                tw   += a[114 + b];
                twlp += a[224 + b];
                if (cum >= (float)MIN_KEPT) break;
            }
            l = twlp / tw;
        }
        loss[pr] = l;
    }
    out[0] = 0.4f * loss[0] + loss[1];
}

extern "C" void kernel_launch(void* const* d_in, const int* in_sizes, int n_in,
                              void* d_out, int out_size, void* d_ws, size_t ws_size,
                              hipStream_t stream)
{
    const float* pred1  = (const float*)d_in[0];
    const float* pred2  = (const float*)d_in[1];
    const int*   target = (const int*)d_in[2];
    float* out = (float*)d_out;
    float* ws  = (float*)d_ws;

    // zero hist (ws[0..2047]) + striped sets (ws[2048..3071])
    hipMemsetAsync(d_ws, 0, 3072 * sizeof(float), stream);

    ohem_row<<<dim3(N_BATCH * H_OUT), 256, 0, stream>>>(pred1, pred2, target, ws);
    ohem_finalize<<<1, 64, 0, stream>>>(ws, out);
}